// Round 3
// baseline (845.382 us; speedup 1.0000x reference)
//
#include <hip/hip_runtime.h>
#include <hip/hip_bf16.h>
#include <stdint.h>

#define IN_F   4096
#define OUT_F  4096
#define BATCH  8192
#define CAP    492

typedef __bf16 v8bf __attribute__((ext_vector_type(8)));
typedef __bf16 v4bf __attribute__((ext_vector_type(4)));
typedef float  v4f  __attribute__((ext_vector_type(4)));

// proper addrspace casts (addrspacecast, NOT integer truncation)
#define GPTR(p) ((const __attribute__((address_space(1))) void*)(p))
#define LPTR(p) ((__attribute__((address_space(3))) void*)(p))

// ---------------------------------------------------------------------------
// convert: X fp32 -> bf16. UNCHANGED.
// ---------------------------------------------------------------------------
__global__ __launch_bounds__(256) void convert_kernel(
    const float4* __restrict__ X4,      // [BATCH*IN_F/4]
    v4bf* __restrict__ Xb4)             // [BATCH*IN_F/4]
{
    const int t = threadIdx.x;
    const size_t base = (size_t)blockIdx.x * 8192 + t;
    #pragma unroll
    for (int u = 0; u < 4; ++u) {
        float4 f[8];
        #pragma unroll
        for (int j = 0; j < 8; ++j)
            f[j] = X4[base + (size_t)(u * 8 + j) * 256];
        #pragma unroll
        for (int j = 0; j < 8; ++j) {
            v4bf o;
            o[0] = (__bf16)f[j].x; o[1] = (__bf16)f[j].y;
            o[2] = (__bf16)f[j].z; o[3] = (__bf16)f[j].w;
            Xb4[base + (size_t)(u * 8 + j) * 256] = o;
        }
    }
}

// ---------------------------------------------------------------------------
// densify: padded CSR -> dense bf16 W. UNCHANGED.
// ---------------------------------------------------------------------------
__global__ __launch_bounds__(256) void densify_kernel(
    const float* __restrict__ values,   // [OUT_F, CAP] fp32
    const int* __restrict__ col_idx,    // [OUT_F, CAP]
    __hip_bfloat16* __restrict__ W)     // [OUT_F, IN_F] bf16 out
{
    __shared__ float rowf[2 * IN_F];    // 32 KiB
    const int t = threadIdx.x;

    #pragma unroll
    for (int i = 0; i < (2 * IN_F) / 256; ++i)
        rowf[t + i * 256] = 0.0f;
    __syncthreads();

    const int r    = t >> 7;
    const int j    = t & 127;
    const int o    = blockIdx.x * 2 + r;
    const int base = o * CAP;
    for (int k = j; k < CAP; k += 128) {
        float v = values[base + k];
        int   c = col_idx[base + k];
        if (v != 0.0f)
            atomicAdd(&rowf[r * IN_F + c], v);
    }
    __syncthreads();

    __hip_bfloat162* W2 = reinterpret_cast<__hip_bfloat162*>(W)
                        + (size_t)blockIdx.x * IN_F;
    #pragma unroll
    for (int i = 0; i < IN_F / 256; ++i) {
        int idx = t + i * 256;
        __hip_bfloat162 h2;
        h2.x = __float2bfloat16(rowf[2 * idx]);
        h2.y = __float2bfloat16(rowf[2 * idx + 1]);
        W2[idx] = h2;
    }
}

// ---------------------------------------------------------------------------
// GEMM + bias, 256x256 tile, BK=64 split into TWO K-HALVES (32 k each).
// 8 waves (2M x 4N), per-wave 128x64 out = acc[8][4].
// LDS 128 KiB = 2 buf x {A-kh0, A-kh1, B-kh0, B-kh1} x 16 KiB.
//   region(b,op,kh) = b*4 + op*2 + kh   (granule units of 1024 per region)
//   A region: 256 rows x 4 granules (granule = 8 bf16 = 16 B).
//
// Pipeline invariant (uniform 4-phase latency cover, never drains below 8):
//   entering kt: outstanding = H(kt).kh0 (4 loads) + H(kt).kh1 (4)
//   ph0: stage H(kt+1).kh0 -> 12; vmcnt(8) drains H(kt).kh0 (issued 4 phases
//        ago at kt-1.ph0); barrier; compute kh0 (2 x 16-MFMA clusters,
//        B frags read once and register-reused).
//   ph2: stage H(kt+1).kh1 -> 12; vmcnt(8) drains H(kt).kh1; barrier;
//        compute kh1.
// 2 barriers / K-tile. Hazards: stages target buf^1 while reads hit buf;
// a region's last read always precedes an intervening barrier before its
// next write-issue (checked for all 4 regions x both buffers).
//
// Bank swizzle (4-granule rows): physical granule = r*4 + (g ^ s(r)),
// s(r) = (r + (r>>2)) & 3. For each 16-lane (ml) group at fixed q, the 8
// bank-quads are each hit exactly 2x -> 2-way = free (m136). Staging
// pre-swizzles the GLOBAL source granule; LDS dest stays linear (m104 rule).
// ---------------------------------------------------------------------------

#define STAGE(nb, kh, ktn)                                                     \
  {                                                                            \
    const __hip_bfloat16* sA = gAs + (ktn) * 64 + (kh) * 32;                   \
    const __hip_bfloat16* sB = gBs + (ktn) * 64 + (kh) * 32;                   \
    __builtin_amdgcn_global_load_lds(GPTR(sA),                                 \
        LPTR(&smem[((nb)*4 + (kh))*1024 + 0   + wave*64]), 16, 0, 0);          \
    __builtin_amdgcn_global_load_lds(GPTR(sA + (size_t)128 * IN_F),            \
        LPTR(&smem[((nb)*4 + (kh))*1024 + 512 + wave*64]), 16, 0, 0);          \
    __builtin_amdgcn_global_load_lds(GPTR(sB),                                 \
        LPTR(&smem[((nb)*4 + 2 + (kh))*1024 + 0   + wave*64]), 16, 0, 0);      \
    __builtin_amdgcn_global_load_lds(GPTR(sB + (size_t)128 * IN_F),            \
        LPTR(&smem[((nb)*4 + 2 + (kh))*1024 + 512 + wave*64]), 16, 0, 0);      \
  }

#define WAITBAR(n)                                                             \
  {                                                                            \
    asm volatile("s_waitcnt vmcnt(" #n ")" ::: "memory");                      \
    __builtin_amdgcn_sched_barrier(0);                                         \
    __builtin_amdgcn_s_barrier();                                              \
  }

#define PHASE_PAIR(bb, kh)                                                     \
  {                                                                            \
    const int regA = ((bb)*4 + (kh)) * 1024;                                   \
    const int regB = ((bb)*4 + 2 + (kh)) * 1024;                               \
    v8bf Bfr[4], Afr[4];                                                       \
    _Pragma("unroll")                                                          \
    for (int nf = 0; nf < 4; ++nf)                                             \
      Bfr[nf] = *reinterpret_cast<const v8bf*>(&smem[regB + bG[nf]]);          \
    _Pragma("unroll")                                                          \
    for (int mf = 0; mf < 4; ++mf)                                             \
      Afr[mf] = *reinterpret_cast<const v8bf*>(&smem[regA + aG[mf]]);          \
    __builtin_amdgcn_s_setprio(1);                                             \
    _Pragma("unroll")                                                          \
    for (int mf = 0; mf < 4; ++mf)                                             \
      _Pragma("unroll")                                                        \
      for (int nf = 0; nf < 4; ++nf)                                           \
        acc[mf][nf] = __builtin_amdgcn_mfma_f32_16x16x32_bf16(                 \
            Afr[mf], Bfr[nf], acc[mf][nf], 0, 0, 0);                           \
    __builtin_amdgcn_s_setprio(0);                                             \
    _Pragma("unroll")                                                          \
    for (int mf = 0; mf < 4; ++mf)                                             \
      Afr[mf] = *reinterpret_cast<const v8bf*>(&smem[regA + aG[4 + mf]]);      \
    __builtin_amdgcn_s_setprio(1);                                             \
    _Pragma("unroll")                                                          \
    for (int mf = 0; mf < 4; ++mf)                                             \
      _Pragma("unroll")                                                        \
      for (int nf = 0; nf < 4; ++nf)                                           \
        acc[4 + mf][nf] = __builtin_amdgcn_mfma_f32_16x16x32_bf16(             \
            Afr[mf], Bfr[nf], acc[4 + mf][nf], 0, 0, 0);                       \
    __builtin_amdgcn_s_setprio(0);                                             \
  }

__global__ __launch_bounds__(512, 2) void gemm_bias_kernel(
    const __hip_bfloat16* __restrict__ X,     // [BATCH, IN_F] bf16
    const __hip_bfloat16* __restrict__ W,     // [OUT_F, IN_F] bf16
    const float* __restrict__ bias,           // [OUT_F] fp32
    float* __restrict__ Y)                    // [BATCH, OUT_F] fp32
{
    __shared__ uint4 smem[8192];              // 128 KiB

    const int t    = threadIdx.x;             // 0..511
    const int wave = t >> 6;
    const int lane = t & 63;
    const int ml   = lane & 15;
    const int q    = lane >> 4;
    const int wm   = wave >> 2;               // 0..1  (M)
    const int wn   = wave & 3;                // 0..3  (N)

    // XCD-aware swizzle (512 wgs % 8 == 0 -> bijective): XCD x owns bn {2x,2x+1}
    const int flat = blockIdx.y * 16 + blockIdx.x;   // 0..511
    const int u    = (flat & 7) * 64 + (flat >> 3);
    const int bn   = u >> 5;                  // 0..15
    const int bm   = u & 31;                  // 0..31

    // staging source: thread t -> row srow = t>>2 (+128 for 2nd inst),
    // physical granule gp = t&3 holds logical g = gp ^ s(row); s(row)=s(srow)
    // since 128 = 0 mod 4 and 128>>2 = 32 = 0 mod 4.
    const int srow = t >> 2;                  // 0..127
    const int sg   = (t & 3) ^ ((srow + (srow >> 2)) & 3);
    const __hip_bfloat16* gAs = X + (size_t)(bm * 256 + srow) * IN_F + sg * 8;
    const __hip_bfloat16* gBs = W + (size_t)(bn * 256 + srow) * IN_F + sg * 8;

    // fragment read granule offsets (within a region)
    int aG[8], bG[4];
    #pragma unroll
    for (int mf = 0; mf < 8; ++mf) {
        const int ar = wm * 128 + mf * 16 + ml;
        aG[mf] = ar * 4 + (q ^ ((ar + (ar >> 2)) & 3));
    }
    #pragma unroll
    for (int nf = 0; nf < 4; ++nf) {
        const int br = wn * 64 + nf * 16 + ml;
        bG[nf] = br * 4 + (q ^ ((br + (br >> 2)) & 3));
    }

    v4f acc[8][4] = {};

    // prologue: stage both k-halves of kt=0 into buf 0 (8 loads/thread)
    STAGE(0, 0, 0);
    STAGE(0, 1, 0);

    for (int kt = 0; kt < 63; ++kt) {
        const int bb = kt & 1;
        const int nb = bb ^ 1;
        STAGE(nb, 0, kt + 1);
        WAITBAR(8);                 // drains H(kt).kh0 (4-phase flight)
        if (bb) { PHASE_PAIR(1, 0); } else { PHASE_PAIR(0, 0); }
        STAGE(nb, 1, kt + 1);
        WAITBAR(8);                 // drains H(kt).kh1 (4-phase flight)
        if (bb) { PHASE_PAIR(1, 1); } else { PHASE_PAIR(0, 1); }
    }
    // kt = 63 (buf 1): no staging; drain incrementally.
    WAITBAR(4);
    PHASE_PAIR(1, 0);
    WAITBAR(0);
    PHASE_PAIR(1, 1);

    // epilogue: C/D layout (m89/m91): col = lane&15, row = q*4 + reg
    float bf4[4];
    #pragma unroll
    for (int nf = 0; nf < 4; ++nf)
        bf4[nf] = bias[bn * 256 + wn * 64 + nf * 16 + ml];

    #pragma unroll
    for (int mf = 0; mf < 8; ++mf) {
        const int row0 = bm * 256 + wm * 128 + mf * 16 + q * 4;
        #pragma unroll
        for (int nf = 0; nf < 4; ++nf) {
            const int col = bn * 256 + wn * 64 + nf * 16 + ml;
            float* yp = Y + (size_t)row0 * OUT_F + col;
            #pragma unroll
            for (int r = 0; r < 4; ++r)
                yp[(size_t)r * OUT_F] = acc[mf][nf][r] + bf4[nf];
        }
    }
}

// ---------------------------------------------------------------------------
// Fallback (ws too small for 96 MiB): fp32 LDS-staged gather.
// ---------------------------------------------------------------------------
__global__ __launch_bounds__(256) void fallback_kernel(
    const float* __restrict__ x,
    const float* __restrict__ values,
    const int* __restrict__ col_idx,
    const float* __restrict__ bias,
    float* __restrict__ y)
{
    __shared__ float xrow[IN_F];
    const int b = blockIdx.y;
    const int t = threadIdx.x;
    for (int i = t; i < IN_F; i += 256)
        xrow[i] = x[(size_t)b * IN_F + i];
    __syncthreads();
    const int o    = blockIdx.x * 256 + t;
    const int base = o * CAP;
    float acc = bias[o];
    for (int k = 0; k < CAP; ++k)
        acc += values[base + k] * xrow[col_idx[base + k]];
    y[(size_t)b * OUT_F + o] = acc;
}

extern "C" void kernel_launch(void* const* d_in, const int* in_sizes, int n_in,
                              void* d_out, int out_size, void* d_ws, size_t ws_size,
                              hipStream_t stream)
{
    const float* x      = (const float*)d_in[0];
    const float* values = (const float*)d_in[1];
    const int*   colidx = (const int*)d_in[2];
    const float* bias   = (const float*)d_in[3];
    float*       y      = (float*)d_out;

    const size_t w_bytes  = (size_t)OUT_F * IN_F * sizeof(__hip_bfloat16);  // 32 MiB
    const size_t xb_bytes = (size_t)BATCH * IN_F * sizeof(__hip_bfloat16);  // 64 MiB
    if (ws_size >= w_bytes + xb_bytes) {
        __hip_bfloat16* W  = (__hip_bfloat16*)d_ws;
        __hip_bfloat16* Xb = (__hip_bfloat16*)((char*)d_ws + w_bytes);

        convert_kernel<<<(BATCH * IN_F / 4) / 8192, 256, 0, stream>>>(
            (const float4*)x, (v4bf*)Xb);
        densify_kernel<<<OUT_F / 2, 256, 0, stream>>>(values, colidx, W);

        dim3 grid(OUT_F / 256, BATCH / 256);
        gemm_bias_kernel<<<grid, 512, 0, stream>>>(Xb, W, bias, y);
    } else {
        dim3 grid(OUT_F / 256, BATCH);
        fallback_kernel<<<grid, 256, 0, stream>>>(x, values, colidx, bias, y);
    }
}

// Round 5
// 465.419 us; speedup vs baseline: 1.8164x; 1.8164x over previous
//
#include <hip/hip_runtime.h>
#include <hip/hip_bf16.h>
#include <stdint.h>

#define IN_F   4096
#define OUT_F  4096
#define BATCH  8192
#define CAP    492

typedef __bf16 v8bf __attribute__((ext_vector_type(8)));
typedef __bf16 v4bf __attribute__((ext_vector_type(4)));
typedef float  v4f  __attribute__((ext_vector_type(4)));

// proper addrspace casts (addrspacecast, NOT integer truncation)
#define GPTR(p) ((const __attribute__((address_space(1))) void*)(p))
#define LPTR(p) ((__attribute__((address_space(3))) void*)(p))

// ---------------------------------------------------------------------------
// convert: X fp32 -> bf16. UNCHANGED.
// ---------------------------------------------------------------------------
__global__ __launch_bounds__(256) void convert_kernel(
    const float4* __restrict__ X4,      // [BATCH*IN_F/4]
    v4bf* __restrict__ Xb4)             // [BATCH*IN_F/4]
{
    const int t = threadIdx.x;
    const size_t base = (size_t)blockIdx.x * 8192 + t;
    #pragma unroll
    for (int u = 0; u < 4; ++u) {
        float4 f[8];
        #pragma unroll
        for (int j = 0; j < 8; ++j)
            f[j] = X4[base + (size_t)(u * 8 + j) * 256];
        #pragma unroll
        for (int j = 0; j < 8; ++j) {
            v4bf o;
            o[0] = (__bf16)f[j].x; o[1] = (__bf16)f[j].y;
            o[2] = (__bf16)f[j].z; o[3] = (__bf16)f[j].w;
            Xb4[base + (size_t)(u * 8 + j) * 256] = o;
        }
    }
}

// ---------------------------------------------------------------------------
// densify: padded CSR -> dense bf16 W. UNCHANGED.
// ---------------------------------------------------------------------------
__global__ __launch_bounds__(256) void densify_kernel(
    const float* __restrict__ values,   // [OUT_F, CAP] fp32
    const int* __restrict__ col_idx,    // [OUT_F, CAP]
    __hip_bfloat16* __restrict__ W)     // [OUT_F, IN_F] bf16 out
{
    __shared__ float rowf[2 * IN_F];    // 32 KiB
    const int t = threadIdx.x;

    #pragma unroll
    for (int i = 0; i < (2 * IN_F) / 256; ++i)
        rowf[t + i * 256] = 0.0f;
    __syncthreads();

    const int r    = t >> 7;
    const int j    = t & 127;
    const int o    = blockIdx.x * 2 + r;
    const int base = o * CAP;
    for (int k = j; k < CAP; k += 128) {
        float v = values[base + k];
        int   c = col_idx[base + k];
        if (v != 0.0f)
            atomicAdd(&rowf[r * IN_F + c], v);
    }
    __syncthreads();

    __hip_bfloat162* W2 = reinterpret_cast<__hip_bfloat162*>(W)
                        + (size_t)blockIdx.x * IN_F;
    #pragma unroll
    for (int i = 0; i < IN_F / 256; ++i) {
        int idx = t + i * 256;
        __hip_bfloat162 h2;
        h2.x = __float2bfloat16(rowf[2 * idx]);
        h2.y = __float2bfloat16(rowf[2 * idx + 1]);
        W2[idx] = h2;
    }
}

// ---------------------------------------------------------------------------
// GEMM + bias, 256x256 tile, BK=64 split into TWO K-HALVES (32 k each).
// 8 waves (2M x 4N), per-wave 128x64 out = acc[8][4] (AGPR-resident; all
// register arrays in the hot loop are literal-indexed -- rule #20).
// LDS 128 KiB = 2 buf x {A-kh0, A-kh1, B-kh0, B-kh1} x 16 KiB.
//   region(b,op,kh) = b*4 + op*2 + kh   (1024 granules each; granule = 16 B)
//   A region: 256 rows x 4 granules.
//
// Pipeline (uniform 4-phase flight, never below 8 outstanding loads/wave):
//   entering kt: outstanding = H(kt).kh0 (4) + H(kt).kh1 (4)
//   ph0: stage H(kt+1).kh0 -> 12; vmcnt(8) drains H(kt).kh0 (issued one full
//        K-tile ago); barrier; compute kh0 (32 MFMA).
//   ph1: stage H(kt+1).kh1 -> 12; vmcnt(8) drains H(kt).kh1; barrier;
//        compute kh1.
// 2 barriers/K-tile. Hazards verified: concurrent stage-writes vs frag-reads
// are always disjoint (opposite buffer or different kh); region's last read
// is barrier-separated from its next write-issue.
//
// Bank swizzle: physical granule = r*4 + (g ^ s(r)), s(r) = (r>>1)&3.
// For 16-lane groups (fixed q): quad = (4(ml&1) + (q^((ml>>1)&3)))&7 hits all
// 8 bank-quads exactly 2x -> 2-way = free (m136). All frag rows are
// 16-aligned + ml so swl = q ^ ((ml>>1)&3) is shared by all 12 offsets.
// Staging pre-swizzles the GLOBAL source granule; LDS dest linear (m104).
// ---------------------------------------------------------------------------

#define STAGE(nb, kh, ktn)                                                     \
  {                                                                            \
    const __hip_bfloat16* sA = gAs + (ktn) * 64 + (kh) * 32;                   \
    const __hip_bfloat16* sB = gBs + (ktn) * 64 + (kh) * 32;                   \
    __builtin_amdgcn_global_load_lds(GPTR(sA),                                 \
        LPTR(&smem[((nb)*4 + (kh))*1024 + 0   + t]), 16, 0, 0);                \
    __builtin_amdgcn_global_load_lds(GPTR(sA + (size_t)128 * IN_F),            \
        LPTR(&smem[((nb)*4 + (kh))*1024 + 512 + t]), 16, 0, 0);                \
    __builtin_amdgcn_global_load_lds(GPTR(sB),                                 \
        LPTR(&smem[((nb)*4 + 2 + (kh))*1024 + 0   + t]), 16, 0, 0);            \
    __builtin_amdgcn_global_load_lds(GPTR(sB + (size_t)128 * IN_F),            \
        LPTR(&smem[((nb)*4 + 2 + (kh))*1024 + 512 + t]), 16, 0, 0);            \
  }

#define WAITBAR(n)                                                             \
  {                                                                            \
    asm volatile("s_waitcnt vmcnt(" #n ")" ::: "memory");                      \
    __builtin_amdgcn_sched_barrier(0);                                         \
    __builtin_amdgcn_s_barrier();                                              \
  }

#define LDG(off) (*reinterpret_cast<const v8bf*>(&smem[(off)]))

#define MFMA_ROW(MF, AF)                                                       \
  acc[MF][0] = __builtin_amdgcn_mfma_f32_16x16x32_bf16(AF, B0f, acc[MF][0], 0, 0, 0); \
  acc[MF][1] = __builtin_amdgcn_mfma_f32_16x16x32_bf16(AF, B1f, acc[MF][1], 0, 0, 0); \
  acc[MF][2] = __builtin_amdgcn_mfma_f32_16x16x32_bf16(AF, B2f, acc[MF][2], 0, 0, 0); \
  acc[MF][3] = __builtin_amdgcn_mfma_f32_16x16x32_bf16(AF, B3f, acc[MF][3], 0, 0, 0);

#define HALF_COMPUTE(regA, regB)                                               \
  {                                                                            \
    const int rA = (regA), rB = (regB);                                        \
    v8bf B0f = LDG(rB + bG0), B1f = LDG(rB + bG1);                             \
    v8bf B2f = LDG(rB + bG2), B3f = LDG(rB + bG3);                             \
    v8bf A0f = LDG(rA + aG0), A1f = LDG(rA + aG1);                             \
    v8bf A2f = LDG(rA + aG2), A3f = LDG(rA + aG3);                             \
    __builtin_amdgcn_s_setprio(1);                                             \
    MFMA_ROW(0, A0f) MFMA_ROW(1, A1f) MFMA_ROW(2, A2f) MFMA_ROW(3, A3f)        \
    __builtin_amdgcn_s_setprio(0);                                             \
    A0f = LDG(rA + aG4); A1f = LDG(rA + aG5);                                  \
    A2f = LDG(rA + aG6); A3f = LDG(rA + aG7);                                  \
    __builtin_amdgcn_s_setprio(1);                                             \
    MFMA_ROW(4, A0f) MFMA_ROW(5, A1f) MFMA_ROW(6, A2f) MFMA_ROW(7, A3f)        \
    __builtin_amdgcn_s_setprio(0);                                             \
  }

__global__ __launch_bounds__(512, 2) void gemm_bias_kernel(
    const __hip_bfloat16* __restrict__ X,     // [BATCH, IN_F] bf16
    const __hip_bfloat16* __restrict__ W,     // [OUT_F, IN_F] bf16
    const float* __restrict__ bias,           // [OUT_F] fp32
    float* __restrict__ Y)                    // [BATCH, OUT_F] fp32
{
    __shared__ uint4 smem[8192];              // 128 KiB

    const int t    = threadIdx.x;             // 0..511
    const int wave = t >> 6;
    const int lane = t & 63;
    const int ml   = lane & 15;
    const int q    = lane >> 4;
    const int wm   = wave >> 2;               // 0..1  (M)
    const int wn   = wave & 3;                // 0..3  (N)

    // XCD-aware swizzle (512 wgs % 8 == 0 -> bijective): XCD x owns bn {2x,2x+1}
    const int flat = blockIdx.y * 16 + blockIdx.x;   // 0..511
    const int u    = (flat & 7) * 64 + (flat >> 3);
    const int bn   = u >> 5;                  // 0..15
    const int bm   = u & 31;                  // 0..31

    // staging source: thread t -> rows srow, srow+128; physical granule t&3
    // holds logical granule (t&3) ^ s(srow), s(r) = (r>>1)&3 -> (t>>3)&3.
    const int srow = t >> 2;                  // 0..127
    const int sg   = (t & 3) ^ ((t >> 3) & 3);
    const __hip_bfloat16* gAs = X + (size_t)(bm * 256 + srow) * IN_F + sg * 8;
    const __hip_bfloat16* gBs = W + (size_t)(bn * 256 + srow) * IN_F + sg * 8;

    // fragment read granule offsets (named scalars -- no register arrays)
    const int swl = q ^ ((ml >> 1) & 3);
    const int aG0 = (wm * 128 + 0 * 16 + ml) * 4 + swl;
    const int aG1 = (wm * 128 + 1 * 16 + ml) * 4 + swl;
    const int aG2 = (wm * 128 + 2 * 16 + ml) * 4 + swl;
    const int aG3 = (wm * 128 + 3 * 16 + ml) * 4 + swl;
    const int aG4 = (wm * 128 + 4 * 16 + ml) * 4 + swl;
    const int aG5 = (wm * 128 + 5 * 16 + ml) * 4 + swl;
    const int aG6 = (wm * 128 + 6 * 16 + ml) * 4 + swl;
    const int aG7 = (wm * 128 + 7 * 16 + ml) * 4 + swl;
    const int bG0 = (wn * 64 + 0 * 16 + ml) * 4 + swl;
    const int bG1 = (wn * 64 + 1 * 16 + ml) * 4 + swl;
    const int bG2 = (wn * 64 + 2 * 16 + ml) * 4 + swl;
    const int bG3 = (wn * 64 + 3 * 16 + ml) * 4 + swl;

    v4f acc[8][4] = {};   // literal-indexed only -> AGPR-eligible

    // prologue: stage both k-halves of kt=0 into buf 0 (8 loads/thread)
    STAGE(0, 0, 0);
    STAGE(0, 1, 0);

    for (int kt = 0; kt < 63; ++kt) {
        const int bb = kt & 1;
        const int nb = bb ^ 1;
        STAGE(nb, 0, kt + 1);
        WAITBAR(8);                 // drains H(kt).kh0
        HALF_COMPUTE((bb * 4 + 0) * 1024, (bb * 4 + 2) * 1024);
        STAGE(nb, 1, kt + 1);
        WAITBAR(8);                 // drains H(kt).kh1
        HALF_COMPUTE((bb * 4 + 1) * 1024, (bb * 4 + 3) * 1024);
    }
    // kt = 63 (buf 1): no staging; drain incrementally.
    WAITBAR(4);
    HALF_COMPUTE((1 * 4 + 0) * 1024, (1 * 4 + 2) * 1024);
    WAITBAR(0);
    HALF_COMPUTE((1 * 4 + 1) * 1024, (1 * 4 + 3) * 1024);

    // epilogue: C/D layout (m89/m91): col = lane&15, row = q*4 + reg
    float bf4[4];
    #pragma unroll
    for (int nf = 0; nf < 4; ++nf)
        bf4[nf] = bias[bn * 256 + wn * 64 + nf * 16 + ml];

    #pragma unroll
    for (int mf = 0; mf < 8; ++mf) {
        const int row0 = bm * 256 + wm * 128 + mf * 16 + q * 4;
        #pragma unroll
        for (int nf = 0; nf < 4; ++nf) {
            const int col = bn * 256 + wn * 64 + nf * 16 + ml;
            float* yp = Y + (size_t)row0 * OUT_F + col;
            #pragma unroll
            for (int r = 0; r < 4; ++r)
                yp[(size_t)r * OUT_F] = acc[mf][nf][r] + bf4[nf];
        }
    }
}

// ---------------------------------------------------------------------------
// Fallback (ws too small for 96 MiB): fp32 LDS-staged gather.
// ---------------------------------------------------------------------------
__global__ __launch_bounds__(256) void fallback_kernel(
    const float* __restrict__ x,
    const float* __restrict__ values,
    const int* __restrict__ col_idx,
    const float* __restrict__ bias,
    float* __restrict__ y)
{
    __shared__ float xrow[IN_F];
    const int b = blockIdx.y;
    const int t = threadIdx.x;
    for (int i = t; i < IN_F; i += 256)
        xrow[i] = x[(size_t)b * IN_F + i];
    __syncthreads();
    const int o    = blockIdx.x * 256 + t;
    const int base = o * CAP;
    float acc = bias[o];
    for (int k = 0; k < CAP; ++k)
        acc += values[base + k] * xrow[col_idx[base + k]];
    y[(size_t)b * OUT_F + o] = acc;
}

extern "C" void kernel_launch(void* const* d_in, const int* in_sizes, int n_in,
                              void* d_out, int out_size, void* d_ws, size_t ws_size,
                              hipStream_t stream)
{
    const float* x      = (const float*)d_in[0];
    const float* values = (const float*)d_in[1];
    const int*   colidx = (const int*)d_in[2];
    const float* bias   = (const float*)d_in[3];
    float*       y      = (float*)d_out;

    const size_t w_bytes  = (size_t)OUT_F * IN_F * sizeof(__hip_bfloat16);  // 32 MiB
    const size_t xb_bytes = (size_t)BATCH * IN_F * sizeof(__hip_bfloat16);  // 64 MiB
    if (ws_size >= w_bytes + xb_bytes) {
        __hip_bfloat16* W  = (__hip_bfloat16*)d_ws;
        __hip_bfloat16* Xb = (__hip_bfloat16*)((char*)d_ws + w_bytes);

        convert_kernel<<<(BATCH * IN_F / 4) / 8192, 256, 0, stream>>>(
            (const float4*)x, (v4bf*)Xb);
        densify_kernel<<<OUT_F / 2, 256, 0, stream>>>(values, colidx, W);

        dim3 grid(OUT_F / 256, BATCH / 256);
        gemm_bias_kernel<<<grid, 512, 0, stream>>>(Xb, W, bias, y);
    } else {
        dim3 grid(OUT_F / 256, BATCH);
        fallback_kernel<<<grid, 256, 0, stream>>>(x, values, colidx, bias, y);
    }
}

// Round 6
// 464.695 us; speedup vs baseline: 1.8192x; 1.0016x over previous
//
#include <hip/hip_runtime.h>
#include <hip/hip_bf16.h>
#include <stdint.h>

#define IN_F   4096
#define OUT_F  4096
#define BATCH  8192
#define CAP    492

typedef __bf16 v8bf __attribute__((ext_vector_type(8)));
typedef __bf16 v4bf __attribute__((ext_vector_type(4)));
typedef float  v4f  __attribute__((ext_vector_type(4)));

// proper addrspace casts (addrspacecast, NOT integer truncation)
#define GPTR(p) ((const __attribute__((address_space(1))) void*)(p))
#define LPTR(p) ((__attribute__((address_space(3))) void*)(p))

// ---------------------------------------------------------------------------
// convert: X fp32 -> bf16. UNCHANGED.
// ---------------------------------------------------------------------------
__global__ __launch_bounds__(256) void convert_kernel(
    const float4* __restrict__ X4,      // [BATCH*IN_F/4]
    v4bf* __restrict__ Xb4)             // [BATCH*IN_F/4]
{
    const int t = threadIdx.x;
    const size_t base = (size_t)blockIdx.x * 8192 + t;
    #pragma unroll
    for (int u = 0; u < 4; ++u) {
        float4 f[8];
        #pragma unroll
        for (int j = 0; j < 8; ++j)
            f[j] = X4[base + (size_t)(u * 8 + j) * 256];
        #pragma unroll
        for (int j = 0; j < 8; ++j) {
            v4bf o;
            o[0] = (__bf16)f[j].x; o[1] = (__bf16)f[j].y;
            o[2] = (__bf16)f[j].z; o[3] = (__bf16)f[j].w;
            Xb4[base + (size_t)(u * 8 + j) * 256] = o;
        }
    }
}

// ---------------------------------------------------------------------------
// densify: padded CSR -> dense bf16 W. UNCHANGED.
// ---------------------------------------------------------------------------
__global__ __launch_bounds__(256) void densify_kernel(
    const float* __restrict__ values,   // [OUT_F, CAP] fp32
    const int* __restrict__ col_idx,    // [OUT_F, CAP]
    __hip_bfloat16* __restrict__ W)     // [OUT_F, IN_F] bf16 out
{
    __shared__ float rowf[2 * IN_F];    // 32 KiB
    const int t = threadIdx.x;

    #pragma unroll
    for (int i = 0; i < (2 * IN_F) / 256; ++i)
        rowf[t + i * 256] = 0.0f;
    __syncthreads();

    const int r    = t >> 7;
    const int j    = t & 127;
    const int o    = blockIdx.x * 2 + r;
    const int base = o * CAP;
    for (int k = j; k < CAP; k += 128) {
        float v = values[base + k];
        int   c = col_idx[base + k];
        if (v != 0.0f)
            atomicAdd(&rowf[r * IN_F + c], v);
    }
    __syncthreads();

    __hip_bfloat162* W2 = reinterpret_cast<__hip_bfloat162*>(W)
                        + (size_t)blockIdx.x * IN_F;
    #pragma unroll
    for (int i = 0; i < IN_F / 256; ++i) {
        int idx = t + i * 256;
        __hip_bfloat162 h2;
        h2.x = __float2bfloat16(rowf[2 * idx]);
        h2.y = __float2bfloat16(rowf[2 * idx + 1]);
        W2[idx] = h2;
    }
}

// ---------------------------------------------------------------------------
// GEMM + bias, 256x256 tile, BK=64 split into TWO K-HALVES (32 k each).
// 8 waves (2M x 4N), per-wave 128x64 out = acc[8][4] (AGPR-resident; all
// register arrays in the hot loop are literal-indexed -- rule #20).
// LDS 128 KiB = 2 buf x {A-kh0, A-kh1, B-kh0, B-kh1} x 16 KiB.
//   region(b,op,kh) = b*4 + op*2 + kh   (1024 granules each; granule = 16 B)
//
// Pipeline (uniform flight, never below 8 outstanding loads/wave):
//   ph0: stage H(kt+1).kh0 -> 12; vmcnt(8) drains H(kt).kh0 (issued one full
//        K-tile ago); barrier; compute kh0 (32 MFMA).
//   ph1: stage H(kt+1).kh1 -> 12; vmcnt(8) drains H(kt).kh1; barrier;
//        compute kh1.
// Race-freedom: staging always targets the opposite buffer; a region's last
// ds_read is consumed by an MFMA before the phase's trailing barrier, and its
// next write-issue is after that barrier.
//
// Bank swizzle: physical granule = r*4 + (g ^ s(r)), s(r) = (r>>1)&3 ->
// 2-way (free) for all 16-lane read groups; verified 0 conflicts in round 5.
// Staging pre-swizzles the GLOBAL source granule; LDS dest linear (m104).
//
// ROUND-6 CHANGE (only): XCD mapping is now a SQUARE co-residency map.
// Old map: 32 concurrent blocks/XCD shared one B panel but had 32 distinct
// A panels -> ~1 MB/K-tile of beyond-L2 supply per XCD (LLC-served).
// New map: XCD x owns an 8bm x 8bn super-tile; in-XCD order makes the first
// 32 resident blocks a 4bm x 8bn rectangle -> per K-tile slab = 4x32KB (A)
// + 8x32KB (B) = 384 KB, L2-resident with ~10-K-tile drift tolerance.
// Beyond-L2 staging traffic drops ~2.7x.
// ---------------------------------------------------------------------------

#define STAGE(nb, kh, ktn)                                                     \
  {                                                                            \
    const __hip_bfloat16* sA = gAs + (ktn) * 64 + (kh) * 32;                   \
    const __hip_bfloat16* sB = gBs + (ktn) * 64 + (kh) * 32;                   \
    __builtin_amdgcn_global_load_lds(GPTR(sA),                                 \
        LPTR(&smem[((nb)*4 + (kh))*1024 + 0   + t]), 16, 0, 0);                \
    __builtin_amdgcn_global_load_lds(GPTR(sA + (size_t)128 * IN_F),            \
        LPTR(&smem[((nb)*4 + (kh))*1024 + 512 + t]), 16, 0, 0);                \
    __builtin_amdgcn_global_load_lds(GPTR(sB),                                 \
        LPTR(&smem[((nb)*4 + 2 + (kh))*1024 + 0   + t]), 16, 0, 0);            \
    __builtin_amdgcn_global_load_lds(GPTR(sB + (size_t)128 * IN_F),            \
        LPTR(&smem[((nb)*4 + 2 + (kh))*1024 + 512 + t]), 16, 0, 0);            \
  }

#define WAITBAR(n)                                                             \
  {                                                                            \
    asm volatile("s_waitcnt vmcnt(" #n ")" ::: "memory");                      \
    __builtin_amdgcn_sched_barrier(0);                                         \
    __builtin_amdgcn_s_barrier();                                              \
  }

#define LDG(off) (*reinterpret_cast<const v8bf*>(&smem[(off)]))

#define MFMA_ROW(MF, AF)                                                       \
  acc[MF][0] = __builtin_amdgcn_mfma_f32_16x16x32_bf16(AF, B0f, acc[MF][0], 0, 0, 0); \
  acc[MF][1] = __builtin_amdgcn_mfma_f32_16x16x32_bf16(AF, B1f, acc[MF][1], 0, 0, 0); \
  acc[MF][2] = __builtin_amdgcn_mfma_f32_16x16x32_bf16(AF, B2f, acc[MF][2], 0, 0, 0); \
  acc[MF][3] = __builtin_amdgcn_mfma_f32_16x16x32_bf16(AF, B3f, acc[MF][3], 0, 0, 0);

#define HALF_COMPUTE(regA, regB)                                               \
  {                                                                            \
    const int rA = (regA), rB = (regB);                                        \
    v8bf B0f = LDG(rB + bG0), B1f = LDG(rB + bG1);                             \
    v8bf B2f = LDG(rB + bG2), B3f = LDG(rB + bG3);                             \
    v8bf A0f = LDG(rA + aG0), A1f = LDG(rA + aG1);                             \
    v8bf A2f = LDG(rA + aG2), A3f = LDG(rA + aG3);                             \
    __builtin_amdgcn_s_setprio(1);                                             \
    MFMA_ROW(0, A0f) MFMA_ROW(1, A1f) MFMA_ROW(2, A2f) MFMA_ROW(3, A3f)        \
    __builtin_amdgcn_s_setprio(0);                                             \
    A0f = LDG(rA + aG4); A1f = LDG(rA + aG5);                                  \
    A2f = LDG(rA + aG6); A3f = LDG(rA + aG7);                                  \
    __builtin_amdgcn_s_setprio(1);                                             \
    MFMA_ROW(4, A0f) MFMA_ROW(5, A1f) MFMA_ROW(6, A2f) MFMA_ROW(7, A3f)        \
    __builtin_amdgcn_s_setprio(0);                                             \
  }

__global__ __launch_bounds__(512, 2) void gemm_bias_kernel(
    const __hip_bfloat16* __restrict__ X,     // [BATCH, IN_F] bf16
    const __hip_bfloat16* __restrict__ W,     // [OUT_F, IN_F] bf16
    const float* __restrict__ bias,           // [OUT_F] fp32
    float* __restrict__ Y)                    // [BATCH, OUT_F] fp32
{
    __shared__ uint4 smem[8192];              // 128 KiB

    const int t    = threadIdx.x;             // 0..511
    const int wave = t >> 6;
    const int lane = t & 63;
    const int ml   = lane & 15;
    const int q    = lane >> 4;
    const int wm   = wave >> 2;               // 0..1  (M)
    const int wn   = wave & 3;                // 0..3  (N)

    // Square co-residency XCD map (round-6 change): XCD x = flat&7 owns an
    // 8bm x 8bn super-tile; first 32 resident blocks per XCD = 4bm x 8bn.
    const int flat = blockIdx.y * 16 + blockIdx.x;   // 0..511
    const int xcd  = flat & 7;
    const int g    = flat >> 3;               // 0..63 within XCD
    const int bm   = (xcd >> 1) * 8 + (g >> 3);      // 0..31
    const int bn   = (xcd & 1) * 8 + (g & 7);        // 0..15

    // staging source: thread t -> rows srow, srow+128; physical granule t&3
    // holds logical granule (t&3) ^ s(srow), s(r) = (r>>1)&3 -> (t>>3)&3.
    const int srow = t >> 2;                  // 0..127
    const int sg   = (t & 3) ^ ((t >> 3) & 3);
    const __hip_bfloat16* gAs = X + (size_t)(bm * 256 + srow) * IN_F + sg * 8;
    const __hip_bfloat16* gBs = W + (size_t)(bn * 256 + srow) * IN_F + sg * 8;

    // fragment read granule offsets (named scalars -- no register arrays)
    const int swl = q ^ ((ml >> 1) & 3);
    const int aG0 = (wm * 128 + 0 * 16 + ml) * 4 + swl;
    const int aG1 = (wm * 128 + 1 * 16 + ml) * 4 + swl;
    const int aG2 = (wm * 128 + 2 * 16 + ml) * 4 + swl;
    const int aG3 = (wm * 128 + 3 * 16 + ml) * 4 + swl;
    const int aG4 = (wm * 128 + 4 * 16 + ml) * 4 + swl;
    const int aG5 = (wm * 128 + 5 * 16 + ml) * 4 + swl;
    const int aG6 = (wm * 128 + 6 * 16 + ml) * 4 + swl;
    const int aG7 = (wm * 128 + 7 * 16 + ml) * 4 + swl;
    const int bG0 = (wn * 64 + 0 * 16 + ml) * 4 + swl;
    const int bG1 = (wn * 64 + 1 * 16 + ml) * 4 + swl;
    const int bG2 = (wn * 64 + 2 * 16 + ml) * 4 + swl;
    const int bG3 = (wn * 64 + 3 * 16 + ml) * 4 + swl;

    v4f acc[8][4] = {};   // literal-indexed only -> AGPR-eligible

    // prologue: stage both k-halves of kt=0 into buf 0 (8 loads/thread)
    STAGE(0, 0, 0);
    STAGE(0, 1, 0);

    for (int kt = 0; kt < 63; ++kt) {
        const int bb = kt & 1;
        const int nb = bb ^ 1;
        STAGE(nb, 0, kt + 1);
        WAITBAR(8);                 // drains H(kt).kh0
        HALF_COMPUTE((bb * 4 + 0) * 1024, (bb * 4 + 2) * 1024);
        STAGE(nb, 1, kt + 1);
        WAITBAR(8);                 // drains H(kt).kh1
        HALF_COMPUTE((bb * 4 + 1) * 1024, (bb * 4 + 3) * 1024);
    }
    // kt = 63 (buf 1): no staging; drain incrementally.
    WAITBAR(4);
    HALF_COMPUTE((1 * 4 + 0) * 1024, (1 * 4 + 2) * 1024);
    WAITBAR(0);
    HALF_COMPUTE((1 * 4 + 1) * 1024, (1 * 4 + 3) * 1024);

    // epilogue: C/D layout (m89/m91): col = lane&15, row = q*4 + reg
    float bf4[4];
    #pragma unroll
    for (int nf = 0; nf < 4; ++nf)
        bf4[nf] = bias[bn * 256 + wn * 64 + nf * 16 + ml];

    #pragma unroll
    for (int mf = 0; mf < 8; ++mf) {
        const int row0 = bm * 256 + wm * 128 + mf * 16 + q * 4;
        #pragma unroll
        for (int nf = 0; nf < 4; ++nf) {
            const int col = bn * 256 + wn * 64 + nf * 16 + ml;
            float* yp = Y + (size_t)row0 * OUT_F + col;
            #pragma unroll
            for (int r = 0; r < 4; ++r)
                yp[(size_t)r * OUT_F] = acc[mf][nf][r] + bf4[nf];
        }
    }
}

// ---------------------------------------------------------------------------
// Fallback (ws too small for 96 MiB): fp32 LDS-staged gather.
// ---------------------------------------------------------------------------
__global__ __launch_bounds__(256) void fallback_kernel(
    const float* __restrict__ x,
    const float* __restrict__ values,
    const int* __restrict__ col_idx,
    const float* __restrict__ bias,
    float* __restrict__ y)
{
    __shared__ float xrow[IN_F];
    const int b = blockIdx.y;
    const int t = threadIdx.x;
    for (int i = t; i < IN_F; i += 256)
        xrow[i] = x[(size_t)b * IN_F + i];
    __syncthreads();
    const int o    = blockIdx.x * 256 + t;
    const int base = o * CAP;
    float acc = bias[o];
    for (int k = 0; k < CAP; ++k)
        acc += values[base + k] * xrow[col_idx[base + k]];
    y[(size_t)b * OUT_F + o] = acc;
}

extern "C" void kernel_launch(void* const* d_in, const int* in_sizes, int n_in,
                              void* d_out, int out_size, void* d_ws, size_t ws_size,
                              hipStream_t stream)
{
    const float* x      = (const float*)d_in[0];
    const float* values = (const float*)d_in[1];
    const int*   colidx = (const int*)d_in[2];
    const float* bias   = (const float*)d_in[3];
    float*       y      = (float*)d_out;

    const size_t w_bytes  = (size_t)OUT_F * IN_F * sizeof(__hip_bfloat16);  // 32 MiB
    const size_t xb_bytes = (size_t)BATCH * IN_F * sizeof(__hip_bfloat16);  // 64 MiB
    if (ws_size >= w_bytes + xb_bytes) {
        __hip_bfloat16* W  = (__hip_bfloat16*)d_ws;
        __hip_bfloat16* Xb = (__hip_bfloat16*)((char*)d_ws + w_bytes);

        convert_kernel<<<(BATCH * IN_F / 4) / 8192, 256, 0, stream>>>(
            (const float4*)x, (v4bf*)Xb);
        densify_kernel<<<OUT_F / 2, 256, 0, stream>>>(values, colidx, W);

        dim3 grid(OUT_F / 256, BATCH / 256);
        gemm_bias_kernel<<<grid, 512, 0, stream>>>(Xb, W, bias, y);
    } else {
        dim3 grid(OUT_F / 256, BATCH);
        fallback_kernel<<<grid, 256, 0, stream>>>(x, values, colidx, bias, y);
    }
}